// Round 1
// baseline (284.139 us; speedup 1.0000x reference)
//
#include <hip/hip_runtime.h>

#define D_MODEL 512
#define P_DIM 64
#define C_DIM 32
#define B_DIM 32
#define N_PATCH 2048   // C_DIM * P_DIM
#define SELECT_N 256

// ---------------------------------------------------------------------------
// Kernel 1: scores[b*2048 + c*64 + p] = sum_d x[b,c,d,p] * w[d]
// One block per (b,c). 256 threads: pg = tid&15 (float4 group over p),
// slice = tid>>4 (16 slices of 32 d each). 16B/lane coalesced loads.
// Bias omitted: constant offset does not affect top-k selection/order,
// and the final output is raw x values, not scores.
// ---------------------------------------------------------------------------
__global__ __launch_bounds__(256) void scores_kernel(
    const float* __restrict__ x, const float* __restrict__ w,
    float* __restrict__ scores) {
  __shared__ float wl[D_MODEL];
  __shared__ float4 red[16][16];

  const int bc  = blockIdx.x;      // b*32 + c
  const int tid = threadIdx.x;

  for (int j = tid; j < D_MODEL; j += 256) wl[j] = w[j];
  __syncthreads();

  const int pg    = tid & 15;      // p-group: covers p = 4*pg .. 4*pg+3
  const int slice = tid >> 4;      // d-slice: d = slice*32 .. slice*32+31

  const float* base = x + (size_t)bc * D_MODEL * P_DIM + pg * 4;
  float4 acc = make_float4(0.f, 0.f, 0.f, 0.f);
#pragma unroll 8
  for (int dd = 0; dd < 32; ++dd) {
    const int d = slice * 32 + dd;
    const float wd = wl[d];
    const float4 v = *(const float4*)(base + (size_t)d * P_DIM);
    acc.x += v.x * wd; acc.y += v.y * wd; acc.z += v.z * wd; acc.w += v.w * wd;
  }
  red[slice][pg] = acc;
  __syncthreads();

  if (tid < 16) {
    float4 s = red[0][tid];
#pragma unroll
    for (int k = 1; k < 16; ++k) {
      const float4 t = red[k][tid];
      s.x += t.x; s.y += t.y; s.z += t.z; s.w += t.w;
    }
    float* sc = scores + (size_t)bc * P_DIM + tid * 4;
    sc[0] = s.x; sc[1] = s.y; sc[2] = s.z; sc[3] = s.w;
  }
}

// ---------------------------------------------------------------------------
// Kernel 2: per-batch full bitonic sort of 2048 (score, idx) packed into
// uint64 keys: (monotone_float_bits << 32) | (2047 - idx).
// Descending key order == descending score, ties -> lower idx first
// (exactly jax.lax.top_k semantics). Top 256 indices written out.
// ---------------------------------------------------------------------------
__global__ __launch_bounds__(1024) void topk_kernel(
    const float* __restrict__ scores, int* __restrict__ topk) {
  __shared__ unsigned long long key[N_PATCH];
  const int b   = blockIdx.x;
  const int tid = threadIdx.x;   // 1024 threads

  for (int j = tid; j < N_PATCH; j += 1024) {
    const float s = scores[(size_t)b * N_PATCH + j];
    unsigned u = __float_as_uint(s);
    // monotone map: larger float -> larger uint
    u ^= (u & 0x80000000u) ? 0xFFFFFFFFu : 0x80000000u;
    key[j] = ((unsigned long long)u << 32) | (unsigned)(N_PATCH - 1 - j);
  }
  __syncthreads();

  for (int k = 2; k <= N_PATCH; k <<= 1) {
    for (int j = k >> 1; j > 0; j >>= 1) {
#pragma unroll
      for (int t = 0; t < 2; ++t) {
        const int i = tid + t * 1024;
        const int ixj = i ^ j;
        if (ixj > i) {
          const bool desc = (i & k) == 0;   // subsequence direction
          const unsigned long long a = key[i];
          const unsigned long long c = key[ixj];
          const bool sw = desc ? (c > a) : (c < a);
          if (sw) { key[i] = c; key[ixj] = a; }
        }
      }
      __syncthreads();
    }
  }

  if (tid < SELECT_N) {
    topk[b * SELECT_N + tid] = (N_PATCH - 1) - (int)(key[tid] & 0xFFFFFFFFu);
  }
}

// ---------------------------------------------------------------------------
// Kernel 3: out[b, i, d] = x[b, c, d, p] with n = topk[b,i], c = n>>6, p = n&63.
// One block per (b,i); coalesced writes, strided reads (should hit L2/L3:
// x was just streamed and fits in the 256 MiB Infinity Cache).
// ---------------------------------------------------------------------------
__global__ __launch_bounds__(256) void gather_kernel(
    const float* __restrict__ x, const int* __restrict__ topk,
    float* __restrict__ out) {
  const int bi = blockIdx.x;     // b*256 + i
  const int b  = bi >> 8;
  const int n  = topk[bi];
  const int c  = n >> 6;
  const int p  = n & 63;
  const float* src = x + (size_t)(b * C_DIM + c) * D_MODEL * P_DIM + p;
  float* dst = out + (size_t)bi * D_MODEL;
#pragma unroll
  for (int d = threadIdx.x; d < D_MODEL; d += 256) {
    dst[d] = src[(size_t)d * P_DIM];
  }
}

extern "C" void kernel_launch(void* const* d_in, const int* in_sizes, int n_in,
                              void* d_out, int out_size, void* d_ws, size_t ws_size,
                              hipStream_t stream) {
  const float* x = (const float*)d_in[0];
  const float* w = (const float*)d_in[1];
  // d_in[2] (bias) intentionally unused: constant shift doesn't change top-k.

  float* scores = (float*)d_ws;                                   // 32*2048*4 = 256 KB
  int*   topk   = (int*)((char*)d_ws + B_DIM * N_PATCH * sizeof(float)); // 32 KB
  float* out    = (float*)d_out;

  scores_kernel<<<B_DIM * C_DIM, 256, 0, stream>>>(x, w, scores);
  topk_kernel<<<B_DIM, 1024, 0, stream>>>(scores, topk);
  gather_kernel<<<B_DIM * SELECT_N, 256, 0, stream>>>(x, topk, out);
}

// Round 2
// 267.648 us; speedup vs baseline: 1.0616x; 1.0616x over previous
//
#include <hip/hip_runtime.h>

#define D_MODEL 512
#define P_DIM 64
#define C_DIM 32
#define B_DIM 32
#define N_PATCH 2048   // C_DIM * P_DIM
#define SELECT_N 256

// ---------------------------------------------------------------------------
// Kernel 1: scores[b*2048 + c*64 + p] = sum_d x[b,c,d,p] * w[d]
// One block per (b,c). 256 threads: pg = tid&15 (float4 group over p),
// slice = tid>>4 (16 slices of 32 d each). 16B/lane coalesced loads.
// Bias omitted: constant offset does not affect top-k selection/order.
// ---------------------------------------------------------------------------
__global__ __launch_bounds__(256) void scores_kernel(
    const float* __restrict__ x, const float* __restrict__ w,
    float* __restrict__ scores) {
  __shared__ float wl[D_MODEL];
  __shared__ float4 red[16][16];

  const int bc  = blockIdx.x;      // b*32 + c
  const int tid = threadIdx.x;

  for (int j = tid; j < D_MODEL; j += 256) wl[j] = w[j];
  __syncthreads();

  const int pg    = tid & 15;      // p-group: covers p = 4*pg .. 4*pg+3
  const int slice = tid >> 4;      // d-slice: d = slice*32 .. slice*32+31

  const float* base = x + (size_t)bc * D_MODEL * P_DIM + pg * 4;
  float4 acc = make_float4(0.f, 0.f, 0.f, 0.f);
#pragma unroll 8
  for (int dd = 0; dd < 32; ++dd) {
    const int d = slice * 32 + dd;
    const float wd = wl[d];
    const float4 v = *(const float4*)(base + (size_t)d * P_DIM);
    acc.x += v.x * wd; acc.y += v.y * wd; acc.z += v.z * wd; acc.w += v.w * wd;
  }
  red[slice][pg] = acc;
  __syncthreads();

  if (tid < 16) {
    float4 s = red[0][tid];
#pragma unroll
    for (int k = 1; k < 16; ++k) {
      const float4 t = red[k][tid];
      s.x += t.x; s.y += t.y; s.z += t.z; s.w += t.w;
    }
    float* sc = scores + (size_t)bc * P_DIM + tid * 4;
    sc[0] = s.x; sc[1] = s.y; sc[2] = s.z; sc[3] = s.w;
  }
}

// ---------------------------------------------------------------------------
// Kernel 2: per-batch bitonic sort of 2048 keys, warp-local for j<=64.
// Key = (monotone_float_bits << 32) | (2047 - idx): descending u64 order ==
// descending score with ties -> lower idx (exact jax.lax.top_k semantics).
// Keys are strictly distinct (index packed in), so max/min CE is exact.
// Layout: thread t holds elements 2t, 2t+1 (adjacent). A 64-lane wave covers
// a 128-element window, so all phases with pair-distance j<=64 run in
// registers via __shfl_xor(j>>1) — no LDS, no barrier. Only j>=128 phases
// (10 of them) touch LDS. Same network + predicate as the round-1-passing
// all-LDS version, just re-executed.
// ---------------------------------------------------------------------------
__global__ __launch_bounds__(1024) void topk_kernel(
    const float* __restrict__ scores, int* __restrict__ topk) {
  __shared__ unsigned long long key[N_PATCH];
  const int b = blockIdx.x;
  const int t = threadIdx.x;   // 1024 threads

  const float2 s2 = *(const float2*)(scores + (size_t)b * N_PATCH + 2 * t);
  unsigned u0 = __float_as_uint(s2.x);
  unsigned u1 = __float_as_uint(s2.y);
  u0 ^= (u0 & 0x80000000u) ? 0xFFFFFFFFu : 0x80000000u;
  u1 ^= (u1 & 0x80000000u) ? 0xFFFFFFFFu : 0x80000000u;
  unsigned long long e0 =
      ((unsigned long long)u0 << 32) | (unsigned)(N_PATCH - 1 - (2 * t));
  unsigned long long e1 =
      ((unsigned long long)u1 << 32) | (unsigned)(N_PATCH - 1 - (2 * t + 1));

  // CE for pair (2t, 2t^j) & (2t+1, (2t+1)^j), j in [2,64]: partner lane t^(j>>1).
  // desc = ((i & k)==0) is identical for both slot indices and both pair sides.
  auto ce_shfl = [&](int j, int k) {
    const bool desc  = ((2 * t) & k) == 0;
    const bool lower = (t & (j >> 1)) == 0;      // my index is the lower of the pair
    const unsigned long long p0 = __shfl_xor(e0, j >> 1, 64);
    const unsigned long long p1 = __shfl_xor(e1, j >> 1, 64);
    const bool keepmax = (lower == desc);        // lower slot keeps max iff desc
    e0 = keepmax ? (e0 > p0 ? e0 : p0) : (e0 < p0 ? e0 : p0);
    e1 = keepmax ? (e1 > p1 ? e1 : p1) : (e1 < p1 ? e1 : p1);
  };
  // j == 1: intra-thread CE of (2t, 2t+1)
  auto ce_intra = [&](int k) {
    const bool desc = ((2 * t) & k) == 0;
    const unsigned long long mx = e0 > e1 ? e0 : e1;
    const unsigned long long mn = e0 > e1 ? e1 : e0;
    e0 = desc ? mx : mn;
    e1 = desc ? mn : mx;
  };

  // Stages k = 2..128: fully warp-local (28 phases, zero barriers).
#pragma unroll
  for (int kk = 1; kk <= 7; ++kk) {
    const int k = 1 << kk;
    for (int j = k >> 1; j >= 2; j >>= 1) ce_shfl(j, k);
    ce_intra(k);
  }

  key[2 * t] = e0; key[2 * t + 1] = e1;
  __syncthreads();

  // Stages k = 256..2048: j>=128 phases in LDS, tail j=64..1 in registers.
#pragma unroll
  for (int kk = 8; kk <= 11; ++kk) {
    const int k = 1 << kk;
    for (int j = k >> 1; j >= 128; j >>= 1) {
#pragma unroll
      for (int q = 0; q < 2; ++q) {
        const int i   = t + q * 1024;
        const int ixj = i ^ j;
        if (ixj > i) {
          const bool desc = (i & k) == 0;
          const unsigned long long a = key[i];
          const unsigned long long c = key[ixj];
          if (desc ? (c > a) : (c < a)) { key[i] = c; key[ixj] = a; }
        }
      }
      __syncthreads();
    }
    e0 = key[2 * t]; e1 = key[2 * t + 1];
#pragma unroll
    for (int j = 64; j >= 2; j >>= 1) ce_shfl(j, k);
    ce_intra(k);
    if (k < N_PATCH) {
      key[2 * t] = e0; key[2 * t + 1] = e1;
      __syncthreads();
    }
  }

  // Final stage k=2048 has desc=true everywhere -> fully descending.
  // Threads 0..127 hold elements 0..255 in registers: write top-256 directly.
  if (t < 128) {
    topk[b * SELECT_N + 2 * t]     = (N_PATCH - 1) - (int)(e0 & 0xFFFFFFFFu);
    topk[b * SELECT_N + 2 * t + 1] = (N_PATCH - 1) - (int)(e1 & 0xFFFFFFFFu);
  }
}

// ---------------------------------------------------------------------------
// Kernel 3: out[b, i, d] = x[b, c, d, p], n = topk[b,i], c = n>>6, p = n&63.
// One block per (b,i); coalesced writes, strided reads (hit L3: x was just
// streamed by scores_kernel and fits in the 256 MiB Infinity Cache).
// ---------------------------------------------------------------------------
__global__ __launch_bounds__(256) void gather_kernel(
    const float* __restrict__ x, const int* __restrict__ topk,
    float* __restrict__ out) {
  const int bi = blockIdx.x;     // b*256 + i
  const int b  = bi >> 8;
  const int n  = topk[bi];
  const int c  = n >> 6;
  const int p  = n & 63;
  const float* src = x + (size_t)(b * C_DIM + c) * D_MODEL * P_DIM + p;
  float* dst = out + (size_t)bi * D_MODEL;
#pragma unroll
  for (int d = threadIdx.x; d < D_MODEL; d += 256) {
    dst[d] = src[(size_t)d * P_DIM];
  }
}

extern "C" void kernel_launch(void* const* d_in, const int* in_sizes, int n_in,
                              void* d_out, int out_size, void* d_ws, size_t ws_size,
                              hipStream_t stream) {
  const float* x = (const float*)d_in[0];
  const float* w = (const float*)d_in[1];
  // d_in[2] (bias) intentionally unused: constant shift doesn't change top-k.

  float* scores = (float*)d_ws;                                        // 256 KB
  int*   topk   = (int*)((char*)d_ws + B_DIM * N_PATCH * sizeof(float)); // 32 KB
  float* out    = (float*)d_out;

  scores_kernel<<<B_DIM * C_DIM, 256, 0, stream>>>(x, w, scores);
  topk_kernel<<<B_DIM, 1024, 0, stream>>>(scores, topk);
  gather_kernel<<<B_DIM * SELECT_N, 256, 0, stream>>>(x, topk, out);
}

// Round 3
// 230.357 us; speedup vs baseline: 1.2335x; 1.1619x over previous
//
#include <hip/hip_runtime.h>

#define D_MODEL 512
#define P_DIM 64
#define C_DIM 32
#define B_DIM 32
#define N_PATCH 2048   // C_DIM * P_DIM
#define SELECT_N 256

// ---------------------------------------------------------------------------
// Kernel 1: scores[b*2048 + c*64 + p] = sum_d x[b,c,d,p] * w[d]
// One block per (b,c). 256 threads: pg = tid&15 (float4 group over p),
// slice = tid>>4 (16 slices of 32 d each). 16B/lane coalesced loads.
// Bias omitted: constant offset does not affect top-k selection/order.
// ---------------------------------------------------------------------------
__global__ __launch_bounds__(256) void scores_kernel(
    const float* __restrict__ x, const float* __restrict__ w,
    float* __restrict__ scores) {
  __shared__ float wl[D_MODEL];
  __shared__ float4 red[16][16];

  const int bc  = blockIdx.x;      // b*32 + c
  const int tid = threadIdx.x;

  for (int j = tid; j < D_MODEL; j += 256) wl[j] = w[j];
  __syncthreads();

  const int pg    = tid & 15;      // p-group: covers p = 4*pg .. 4*pg+3
  const int slice = tid >> 4;      // d-slice: d = slice*32 .. slice*32+31

  const float* base = x + (size_t)bc * D_MODEL * P_DIM + pg * 4;
  float4 acc = make_float4(0.f, 0.f, 0.f, 0.f);
#pragma unroll 8
  for (int dd = 0; dd < 32; ++dd) {
    const int d = slice * 32 + dd;
    const float wd = wl[d];
    const float4 v = *(const float4*)(base + (size_t)d * P_DIM);
    acc.x += v.x * wd; acc.y += v.y * wd; acc.z += v.z * wd; acc.w += v.w * wd;
  }
  red[slice][pg] = acc;
  __syncthreads();

  if (tid < 16) {
    float4 s = red[0][tid];
#pragma unroll
    for (int k = 1; k < 16; ++k) {
      const float4 t = red[k][tid];
      s.x += t.x; s.y += t.y; s.z += t.z; s.w += t.w;
    }
    float* sc = scores + (size_t)bc * P_DIM + tid * 4;
    sc[0] = s.x; sc[1] = s.y; sc[2] = s.z; sc[3] = s.w;
  }
}

// ---------------------------------------------------------------------------
// Kernel 2: per-batch bitonic sort of 2048 keys, warp-local for j<=64.
// Key = (monotone_float_bits << 32) | (2047 - idx): descending u64 order ==
// descending score with ties -> lower idx (exact jax.lax.top_k semantics).
// ---------------------------------------------------------------------------
__global__ __launch_bounds__(1024) void topk_kernel(
    const float* __restrict__ scores, int* __restrict__ topk) {
  __shared__ unsigned long long key[N_PATCH];
  const int b = blockIdx.x;
  const int t = threadIdx.x;   // 1024 threads

  const float2 s2 = *(const float2*)(scores + (size_t)b * N_PATCH + 2 * t);
  unsigned u0 = __float_as_uint(s2.x);
  unsigned u1 = __float_as_uint(s2.y);
  u0 ^= (u0 & 0x80000000u) ? 0xFFFFFFFFu : 0x80000000u;
  u1 ^= (u1 & 0x80000000u) ? 0xFFFFFFFFu : 0x80000000u;
  unsigned long long e0 =
      ((unsigned long long)u0 << 32) | (unsigned)(N_PATCH - 1 - (2 * t));
  unsigned long long e1 =
      ((unsigned long long)u1 << 32) | (unsigned)(N_PATCH - 1 - (2 * t + 1));

  auto ce_shfl = [&](int j, int k) {
    const bool desc  = ((2 * t) & k) == 0;
    const bool lower = (t & (j >> 1)) == 0;
    const unsigned long long p0 = __shfl_xor(e0, j >> 1, 64);
    const unsigned long long p1 = __shfl_xor(e1, j >> 1, 64);
    const bool keepmax = (lower == desc);
    e0 = keepmax ? (e0 > p0 ? e0 : p0) : (e0 < p0 ? e0 : p0);
    e1 = keepmax ? (e1 > p1 ? e1 : p1) : (e1 < p1 ? e1 : p1);
  };
  auto ce_intra = [&](int k) {
    const bool desc = ((2 * t) & k) == 0;
    const unsigned long long mx = e0 > e1 ? e0 : e1;
    const unsigned long long mn = e0 > e1 ? e1 : e0;
    e0 = desc ? mx : mn;
    e1 = desc ? mn : mx;
  };

#pragma unroll
  for (int kk = 1; kk <= 7; ++kk) {
    const int k = 1 << kk;
    for (int j = k >> 1; j >= 2; j >>= 1) ce_shfl(j, k);
    ce_intra(k);
  }

  key[2 * t] = e0; key[2 * t + 1] = e1;
  __syncthreads();

#pragma unroll
  for (int kk = 8; kk <= 11; ++kk) {
    const int k = 1 << kk;
    for (int j = k >> 1; j >= 128; j >>= 1) {
#pragma unroll
      for (int q = 0; q < 2; ++q) {
        const int i   = t + q * 1024;
        const int ixj = i ^ j;
        if (ixj > i) {
          const bool desc = (i & k) == 0;
          const unsigned long long a = key[i];
          const unsigned long long c = key[ixj];
          if (desc ? (c > a) : (c < a)) { key[i] = c; key[ixj] = a; }
        }
      }
      __syncthreads();
    }
    e0 = key[2 * t]; e1 = key[2 * t + 1];
#pragma unroll
    for (int j = 64; j >= 2; j >>= 1) ce_shfl(j, k);
    ce_intra(k);
    if (k < N_PATCH) {
      key[2 * t] = e0; key[2 * t + 1] = e1;
      __syncthreads();
    }
  }

  if (t < 128) {
    topk[b * SELECT_N + 2 * t]     = (N_PATCH - 1) - (int)(e0 & 0xFFFFFFFFu);
    topk[b * SELECT_N + 2 * t + 1] = (N_PATCH - 1) - (int)(e1 & 0xFFFFFFFFu);
  }
}

// ---------------------------------------------------------------------------
// Kernel 3 (v2): inverted gather. One block per (b,c). Scan this batch's
// 256 topk entries for channel c (avg m~8 hits), then stream the whole
// x[b,c,:,:] tile (128 KB, L3-resident after scores pass) through LDS in
// coalesced float4 rows, and write each selected patch coalesced over d
// (256 B per wave-instr). LDS tile padded to 65 -> transpose reads are
// (dd + p) % 32 across lanes = 2-way bank aliasing = free.
// Replaces the scattered stride-256B gather (512 MB of line traffic).
// ---------------------------------------------------------------------------
__global__ __launch_bounds__(256) void gather_kernel(
    const float* __restrict__ x, const int* __restrict__ topk,
    float* __restrict__ out) {
  __shared__ float tile[64][65];
  __shared__ int plist[64];
  __shared__ int ilist[64];
  __shared__ int mcnt;

  const int bc = blockIdx.x;     // b*32 + c
  const int b  = bc >> 5;
  const int c  = bc & 31;
  const int t  = threadIdx.x;    // 256 threads

  if (t == 0) mcnt = 0;
  __syncthreads();

  {
    const int n = topk[b * SELECT_N + t];   // one entry per thread
    if ((n >> 6) == c) {
      const int slot = atomicAdd(&mcnt, 1);
      plist[slot] = n & 63;
      ilist[slot] = t;                       // output rank
    }
  }
  __syncthreads();
  const int m = mcnt;
  if (m == 0) return;

  const float* xb = x + (size_t)bc * (D_MODEL * P_DIM);

  const int p4 = (t & 15) * 4;   // float4 column offset within a row
  const int r0 = t >> 4;         // 0..15: row within 16-row load group
  const int jr = t >> 6;         // 0..3: wave id = patch group for writes
  const int dd = t & 63;         // lane = d offset within chunk for writes

  for (int d0 = 0; d0 < D_MODEL; d0 += 64) {
#pragma unroll
    for (int q = 0; q < 4; ++q) {
      const int drow = r0 + q * 16;
      const float4 v =
          *(const float4*)(xb + (size_t)(d0 + drow) * P_DIM + p4);
      tile[drow][p4]     = v.x;
      tile[drow][p4 + 1] = v.y;
      tile[drow][p4 + 2] = v.z;
      tile[drow][p4 + 3] = v.w;
    }
    __syncthreads();
    for (int j = jr; j < m; j += 4) {
      out[(size_t)(b * SELECT_N + ilist[j]) * D_MODEL + d0 + dd] =
          tile[dd][plist[j]];
    }
    __syncthreads();
  }
}

extern "C" void kernel_launch(void* const* d_in, const int* in_sizes, int n_in,
                              void* d_out, int out_size, void* d_ws, size_t ws_size,
                              hipStream_t stream) {
  const float* x = (const float*)d_in[0];
  const float* w = (const float*)d_in[1];
  // d_in[2] (bias) intentionally unused: constant shift doesn't change top-k.

  float* scores = (float*)d_ws;                                          // 256 KB
  int*   topk   = (int*)((char*)d_ws + B_DIM * N_PATCH * sizeof(float)); // 32 KB
  float* out    = (float*)d_out;

  scores_kernel<<<B_DIM * C_DIM, 256, 0, stream>>>(x, w, scores);
  topk_kernel<<<B_DIM, 1024, 0, stream>>>(scores, topk);
  gather_kernel<<<B_DIM * C_DIM, 256, 0, stream>>>(x, topk, out);
}